// Round 1
// baseline (688.382 us; speedup 1.0000x reference)
//
#include <hip/hip_runtime.h>

#define BDIM 16
#define CDIM 256
#define NDIM 4096
#define CQKD 32

typedef float f32x4 __attribute__((ext_vector_type(4)));
typedef short s16x8 __attribute__((ext_vector_type(8)));

__device__ __forceinline__ unsigned short f2bf(float f) {
  unsigned int u = __builtin_bit_cast(unsigned int, f);
  u += 0x7fffu + ((u >> 16) & 1u);   // RNE to bf16
  return (unsigned short)(u >> 16);
}
__device__ __forceinline__ unsigned int pack2(float a, float b) {
  return (unsigned int)f2bf(a) | ((unsigned int)f2bf(b) << 16);
}

// ---------------------------------------------------------------------------
// Q/K projection: q[b][n][o] = sum_c wq[o][c] * x[b][c][n] + bq[o]
// Output layout [B][N][32] bf16  (== Q and K^T), so attention fragments are
// contiguous 16B loads.
// ---------------------------------------------------------------------------
__global__ __launch_bounds__(256) void qk_proj_kernel(
    const float* __restrict__ x, const float* __restrict__ wq,
    const float* __restrict__ bq, const float* __restrict__ wk,
    const float* __restrict__ bk, unsigned short* __restrict__ Qw,
    unsigned short* __restrict__ Kw) {
  __shared__ __align__(16) float wqt[CDIM * CQKD];  // [c][o]
  __shared__ __align__(16) float wkt[CDIM * CQKD];
  const int tid = threadIdx.x;
  for (int i = tid; i < CDIM * CQKD; i += 256) {
    int o = i >> 8, c = i & 255;          // i = o*256 + c (coalesced read)
    wqt[c * CQKD + o] = wq[i];
    wkt[c * CQKD + o] = wk[i];
  }
  __syncthreads();
  const int b = blockIdx.y;
  const int n = blockIdx.x * 256 + tid;
  const float* xp = x + (size_t)b * CDIM * NDIM + n;
  float aq[CQKD], ak[CQKD];
#pragma unroll
  for (int o = 0; o < CQKD; o++) { aq[o] = 0.f; ak[o] = 0.f; }
  for (int c = 0; c < CDIM; c++) {
    float xv = xp[(size_t)c * NDIM];  // coalesced across threads
#pragma unroll
    for (int o4 = 0; o4 < CQKD / 4; o4++) {
      f32x4 q4 = *reinterpret_cast<const f32x4*>(&wqt[c * CQKD + o4 * 4]);
      f32x4 k4 = *reinterpret_cast<const f32x4*>(&wkt[c * CQKD + o4 * 4]);
#pragma unroll
      for (int i = 0; i < 4; i++) {
        aq[o4 * 4 + i] = fmaf(q4[i], xv, aq[o4 * 4 + i]);
        ak[o4 * 4 + i] = fmaf(k4[i], xv, ak[o4 * 4 + i]);
      }
    }
  }
  uint4* qdst = reinterpret_cast<uint4*>(Qw + ((size_t)b * NDIM + n) * CQKD);
  uint4* kdst = reinterpret_cast<uint4*>(Kw + ((size_t)b * NDIM + n) * CQKD);
#pragma unroll
  for (int v = 0; v < 4; v++) {
    int o = v * 8;
    uint4 tq, tk;
    tq.x = pack2(aq[o + 0] + bq[o + 0], aq[o + 1] + bq[o + 1]);
    tq.y = pack2(aq[o + 2] + bq[o + 2], aq[o + 3] + bq[o + 3]);
    tq.z = pack2(aq[o + 4] + bq[o + 4], aq[o + 5] + bq[o + 5]);
    tq.w = pack2(aq[o + 6] + bq[o + 6], aq[o + 7] + bq[o + 7]);
    tk.x = pack2(ak[o + 0] + bk[o + 0], ak[o + 1] + bk[o + 1]);
    tk.y = pack2(ak[o + 2] + bk[o + 2], ak[o + 3] + bk[o + 3]);
    tk.z = pack2(ak[o + 4] + bk[o + 4], ak[o + 5] + bk[o + 5]);
    tk.w = pack2(ak[o + 6] + bk[o + 6], ak[o + 7] + bk[o + 7]);
    qdst[v] = tq;
    kdst[v] = tk;
  }
}

// ---------------------------------------------------------------------------
// V projection: v[b][c][n] = sum_c' wv[c][c'] * x[b][c'][n] + bv[c]
// Output layout [B][C][N] bf16 (natural; PV A-fragment contiguous along n).
// ---------------------------------------------------------------------------
__global__ __launch_bounds__(256) void v_proj_kernel(
    const float* __restrict__ x, const float* __restrict__ wv,
    const float* __restrict__ bv, unsigned short* __restrict__ Vw) {
  __shared__ __align__(16) float wvt[CDIM * 64];  // [c_in][oo]
  const int tid = threadIdx.x;
  const int o0 = blockIdx.z * 64;
  for (int i = tid; i < CDIM * 64; i += 256) {
    int oo = i >> 8, c = i & 255;  // read wv[(o0+oo)][c] coalesced over c
    wvt[c * 64 + oo] = wv[(size_t)(o0 + oo) * CDIM + c];
  }
  __syncthreads();
  const int b = blockIdx.y;
  const int n = blockIdx.x * 256 + tid;
  const float* xp = x + (size_t)b * CDIM * NDIM + n;
  float acc[64];
#pragma unroll
  for (int i = 0; i < 64; i++) acc[i] = 0.f;
  for (int c = 0; c < CDIM; c++) {
    float xv = xp[(size_t)c * NDIM];
#pragma unroll
    for (int o4 = 0; o4 < 16; o4++) {
      f32x4 w4 = *reinterpret_cast<const f32x4*>(&wvt[c * 64 + o4 * 4]);
#pragma unroll
      for (int i = 0; i < 4; i++)
        acc[o4 * 4 + i] = fmaf(w4[i], xv, acc[o4 * 4 + i]);
    }
  }
#pragma unroll
  for (int oo = 0; oo < 64; oo++) {
    Vw[((size_t)b * CDIM + o0 + oo) * NDIM + n] = f2bf(acc[oo] + bv[o0 + oo]);
  }
}

// ---------------------------------------------------------------------------
// Flash attention + gamma*out + residual.
// Block = (m-tile of 64 rows, batch). 4 waves:
//   phase 1: wave w computes S rows [w*16, w*16+16) (Q frag held in regs),
//            online softmax in-register, writes P(bf16) + scale to LDS.
//   phase 2: each wave PVs its 64-channel slice: Ot[c,m] += V_frag x P^T_frag
//            (swapped operands -> accumulator is O^T -> coalesced epilogue).
// P in LDS is XOR-swizzled (byte ^= (row&7)<<4) to kill the 16-way
// row-stride-128B ds_read_b128 bank conflict.
// ---------------------------------------------------------------------------
__global__ __launch_bounds__(256) void attn_kernel(
    const float* __restrict__ x, const unsigned short* __restrict__ Qw,
    const unsigned short* __restrict__ Kw, const unsigned short* __restrict__ Vw,
    const float* __restrict__ gamma_p, float* __restrict__ out) {
  __shared__ __align__(16) char Plds[64 * 128];   // 64 rows x 64 cols bf16
  __shared__ __align__(16) float scale_lds[64];
  __shared__ __align__(16) float linv_lds[64];

  const int tid = threadIdx.x;
  const int w = tid >> 6;      // wave 0..3
  const int lane = tid & 63;
  const int g = lane >> 4;     // 16-lane group 0..3
  const int lr = lane & 15;

  const int b = blockIdx.y;
  const int m0 = blockIdx.x * 64;
  const int cslice = w * 64;
  const int prow = w * 16 + 4 * g;  // base P-row this lane produces

  // Q A-fragment: A[row=lr][k=8g+j] = Q[m0+w*16+lr][8g+j]
  s16x8 qfrag = *reinterpret_cast<const s16x8*>(
      Qw + ((size_t)b * NDIM + m0 + w * 16 + lr) * CQKD + 8 * g);

  f32x4 acc[4][4];  // [ct][mt]: rows c=cslice+ct*16+4g+j, cols m=m0+mt*16+lr
#pragma unroll
  for (int i = 0; i < 4; i++)
#pragma unroll
    for (int j = 0; j < 4; j++) acc[i][j] = f32x4{0.f, 0.f, 0.f, 0.f};

  float m_run[4], l_run[4];
#pragma unroll
  for (int j = 0; j < 4; j++) { m_run[j] = -1e30f; l_run[j] = 0.f; }

  const unsigned short* kbbase = Kw + (size_t)b * NDIM * CQKD;
  const unsigned short* vbbase = Vw + ((size_t)b * CDIM + cslice) * NDIM;

  for (int n0 = 0; n0 < NDIM; n0 += 64) {
    // ---- phase 1: S = Q K^T for this wave's 16 rows
    f32x4 S[4];
#pragma unroll
    for (int nt = 0; nt < 4; nt++) {
      s16x8 kfrag = *reinterpret_cast<const s16x8*>(
          kbbase + (size_t)(n0 + nt * 16 + lr) * CQKD + 8 * g);
      S[nt] = __builtin_amdgcn_mfma_f32_16x16x32_bf16(
          qfrag, kfrag, f32x4{0.f, 0.f, 0.f, 0.f}, 0, 0, 0);
    }
    // row max (rows m = prow + j), reduce over cols = low 4 lane bits
    float t[4];
#pragma unroll
    for (int j = 0; j < 4; j++)
      t[j] = fmaxf(fmaxf(S[0][j], S[1][j]), fmaxf(S[2][j], S[3][j]));
#pragma unroll
    for (int mask = 1; mask < 16; mask <<= 1) {
#pragma unroll
      for (int j = 0; j < 4; j++) t[j] = fmaxf(t[j], __shfl_xor(t[j], mask, 64));
    }
    float sc[4], rs[4], P[4][4];
#pragma unroll
    for (int j = 0; j < 4; j++) {
      float mn = fmaxf(m_run[j], t[j]);
      sc[j] = exp2f((m_run[j] - mn) * 1.44269504f);
      m_run[j] = mn;
      float s0 = 0.f;
#pragma unroll
      for (int nt = 0; nt < 4; nt++) {
        float p = exp2f((S[nt][j] - mn) * 1.44269504f);
        P[nt][j] = p;
        s0 += p;
      }
      rs[j] = s0;
    }
#pragma unroll
    for (int mask = 1; mask < 16; mask <<= 1) {
#pragma unroll
      for (int j = 0; j < 4; j++) rs[j] += __shfl_xor(rs[j], mask, 64);
    }
#pragma unroll
    for (int j = 0; j < 4; j++) l_run[j] = l_run[j] * sc[j] + rs[j];

    // write P (bf16, swizzled) rows prow+j, cols nt*16+lr
#pragma unroll
    for (int j = 0; j < 4; j++) {
      int r = prow + j;
      int rowbase = r * 128;
      int swz = (r & 7) << 4;
#pragma unroll
      for (int nt = 0; nt < 4; nt++) {
        int off = (rowbase + (nt * 16 + lr) * 2) ^ swz;
        *reinterpret_cast<unsigned short*>(Plds + off) = f2bf(P[nt][j]);
      }
    }
    if (lr == 0) {
      f32x4 v4;
      v4[0] = sc[0]; v4[1] = sc[1]; v4[2] = sc[2]; v4[3] = sc[3];
      *reinterpret_cast<f32x4*>(&scale_lds[prow]) = v4;
    }
    __syncthreads();

    // ---- phase 2: rescale + PV for this wave's channel slice
    float smt[4];
#pragma unroll
    for (int mt = 0; mt < 4; mt++) smt[mt] = scale_lds[mt * 16 + lr];
#pragma unroll
    for (int ct = 0; ct < 4; ct++)
#pragma unroll
      for (int mt = 0; mt < 4; mt++)
#pragma unroll
        for (int j = 0; j < 4; j++) acc[ct][mt][j] *= smt[mt];

#pragma unroll
    for (int ks = 0; ks < 2; ks++) {
      s16x8 pfrag[4];
#pragma unroll
      for (int mt = 0; mt < 4; mt++) {
        int r = mt * 16 + lr;
        int off = (r * 128 + ks * 64 + g * 16) ^ ((r & 7) << 4);
        pfrag[mt] = *reinterpret_cast<const s16x8*>(Plds + off);
      }
#pragma unroll
      for (int ct = 0; ct < 4; ct++) {
        s16x8 vfrag = *reinterpret_cast<const s16x8*>(
            vbbase + (size_t)(ct * 16 + lr) * NDIM + n0 + ks * 32 + 8 * g);
#pragma unroll
        for (int mt = 0; mt < 4; mt++)
          acc[ct][mt] = __builtin_amdgcn_mfma_f32_16x16x32_bf16(
              vfrag, pfrag[mt], acc[ct][mt], 0, 0, 0);
      }
    }
    __syncthreads();
  }

  // finalize: 1/l for the rows this wave owns -> LDS -> all waves
  if (lr == 0) {
    f32x4 v4;
#pragma unroll
    for (int j = 0; j < 4; j++) v4[j] = 1.f / l_run[j];
    *reinterpret_cast<f32x4*>(&linv_lds[prow]) = v4;
  }
  __syncthreads();
  float linv[4];
#pragma unroll
  for (int mt = 0; mt < 4; mt++) linv[mt] = linv_lds[mt * 16 + lr];
  const float gmv = gamma_p[0];
#pragma unroll
  for (int ct = 0; ct < 4; ct++) {
#pragma unroll
    for (int j = 0; j < 4; j++) {
      int c = cslice + ct * 16 + 4 * g + j;
      const size_t rowoff = ((size_t)b * CDIM + c) * NDIM + m0;
#pragma unroll
      for (int mt = 0; mt < 4; mt++) {
        size_t idx = rowoff + mt * 16 + lr;  // 16 consecutive m -> coalesced
        out[idx] = gmv * (acc[ct][mt][j] * linv[mt]) + x[idx];
      }
    }
  }
}

extern "C" void kernel_launch(void* const* d_in, const int* in_sizes, int n_in,
                              void* d_out, int out_size, void* d_ws,
                              size_t ws_size, hipStream_t stream) {
  const float* x  = (const float*)d_in[0];
  const float* wq = (const float*)d_in[1];
  const float* bq = (const float*)d_in[2];
  const float* wk = (const float*)d_in[3];
  const float* bk = (const float*)d_in[4];
  const float* wv = (const float*)d_in[5];
  const float* bv = (const float*)d_in[6];
  const float* gm = (const float*)d_in[7];
  float* out = (float*)d_out;

  // workspace: Q [B][N][32] bf16 (4MB) | K [B][N][32] bf16 (4MB) | V [B][C][N] bf16 (32MB)
  unsigned short* Qw = (unsigned short*)d_ws;
  unsigned short* Kw = Qw + (size_t)BDIM * NDIM * CQKD;
  unsigned short* Vw = Kw + (size_t)BDIM * NDIM * CQKD;

  qk_proj_kernel<<<dim3(NDIM / 256, BDIM), 256, 0, stream>>>(x, wq, bq, wk, bk,
                                                             Qw, Kw);
  v_proj_kernel<<<dim3(NDIM / 256, BDIM, 4), 256, 0, stream>>>(x, wv, bv, Vw);
  attn_kernel<<<dim3(NDIM / 64, BDIM), 256, 0, stream>>>(x, Qw, Kw, Vw, gm, out);
}